// Round 1
// baseline (176.726 us; speedup 1.0000x reference)
//
#include <hip/hip_runtime.h>

// DMS_STAttention reduces algebraically to a broadcast:
//   softmax over the head axis (size 1) == 1.0 everywhere, so
//   sa = 1 + sa_bias (broadcast over B), ta = 1 + ta_bias (broadcast over B).
// src and all weight inputs are dead.

constexpr int B = 2048, T = 10, J = 22;
constexpr int SA_ELEMS = B * T * J * J;   // 9,912,320
constexpr int TA_ELEMS = B * J * T * T;   // 4,505,600
constexpr int SA_P4 = (T * J * J) / 4;    // 4840/4 = 1210  (float4 period, sa)
constexpr int TA_P4 = (J * T * T) / 4;    // 2200/4 = 550   (float4 period, ta)
constexpr int SA_F4 = SA_ELEMS / 4;       // 2,478,080

__global__ void __launch_bounds__(256)
bias_broadcast_kernel(const float4* __restrict__ sa_bias4,
                      const float4* __restrict__ ta_bias4,
                      float4* __restrict__ out4,
                      int tot_f4) {
    int stride = gridDim.x * blockDim.x;
    for (int v = blockIdx.x * blockDim.x + threadIdx.x; v < tot_f4; v += stride) {
        float4 b;
        if (v < SA_F4) {
            b = sa_bias4[v % SA_P4];
        } else {
            b = ta_bias4[(v - SA_F4) % TA_P4];
        }
        b.x += 1.0f; b.y += 1.0f; b.z += 1.0f; b.w += 1.0f;
        out4[v] = b;
    }
}

extern "C" void kernel_launch(void* const* d_in, const int* in_sizes, int n_in,
                              void* d_out, int out_size, void* d_ws, size_t ws_size,
                              hipStream_t stream) {
    // Input order (setup_inputs dict order):
    //  0: src, 1: W_lin_s, 2: a_src_s, 3: a_dst_s, 4: W_edge_s, 5: a_edge_s,
    //  6: W_lin_t, 7: a_src_t, 8: a_dst_t, 9: W_edge_t, 10: a_edge_t,
    // 11: sa_bias [T,J,J], 12: ta_bias [J,T,T]
    const float4* sa_bias4 = (const float4*)d_in[11];
    const float4* ta_bias4 = (const float4*)d_in[12];
    float4* out4 = (float4*)d_out;

    int tot_f4 = out_size / 4;  // 3,604,480
    int block = 256;
    int grid = (tot_f4 + block - 1) / block;
    if (grid > 2048) grid = 2048;  // grid-stride the rest
    bias_broadcast_kernel<<<grid, block, 0, stream>>>(sa_bias4, ta_bias4, out4, tot_f4);
}